// Round 1
// baseline (722.448 us; speedup 1.0000x reference)
//
#include <hip/hip_runtime.h>

#define D 64

// ---------------- zero ----------------
__global__ void zero_kernel(float* __restrict__ p, int n) {
    int i = blockIdx.x * blockDim.x + threadIdx.x;
    if (i < n) p[i] = 0.0f;
}

// ---------------- in-degree count ----------------
__global__ void cnt_kernel(const int* __restrict__ dst, float* __restrict__ cnt, int ne) {
    int i = blockIdx.x * blockDim.x + threadIdx.x;
    if (i < ne) atomicAdd(&cnt[dst[i]], 1.0f);
}

// r[i] = (1/N) / max(cnt[i],1)   (first application, v = u = 1/N * ones)
__global__ void r0_kernel(const float* __restrict__ cnt, float* __restrict__ r, int nn) {
    int i = blockIdx.x * blockDim.x + threadIdx.x;
    if (i < nn) {
        float c = fmaxf(cnt[i], 1.0f);
        r[i] = (1.0f / (float)nn) / c;
    }
}

// r[i] = a[i] / max(cnt[i],1)
__global__ void rdiv_kernel(const float* __restrict__ a, const float* __restrict__ cnt,
                            float* __restrict__ r, int nn) {
    int i = blockIdx.x * blockDim.x + threadIdx.x;
    if (i < nn) {
        float c = fmaxf(cnt[i], 1.0f);
        r[i] = a[i] / c;
    }
}

// a_next[src[e]] += r[dst[e]]   (this is A^T applied to a node-vector)
__global__ void scatter_kernel(const int* __restrict__ src, const int* __restrict__ dst,
                               const float* __restrict__ r, float* __restrict__ an, int ne) {
    int i = blockIdx.x * blockDim.x + threadIdx.x;
    if (i < ne) atomicAdd(&an[src[i]], r[dst[i]]);
}

// X[0..63]   = sum_i x[i,:]            (scale by 1/N later)
// X[64..127] = sum_i a1[i] * x[i,:]
// X[128..]   = sum_i a2[i] * x[i,:]
// X[192..]   = sum_i a3[i] * x[i,:]
// X[256] = sum a1, X[257] = sum a2
__global__ void xpass_kernel(const float* __restrict__ x,
                             const float* __restrict__ a1, const float* __restrict__ a2,
                             const float* __restrict__ a3, float* __restrict__ X, int nn) {
    int col = threadIdx.x & 63;
    int rg  = threadIdx.x >> 6;   // 0..3
    float acc0 = 0.f, acc1 = 0.f, acc2 = 0.f, acc3 = 0.f, ss1 = 0.f, ss2 = 0.f;
    for (int i = blockIdx.x * 4 + rg; i < nn; i += gridDim.x * 4) {
        float xv = x[i * D + col];
        float w1 = a1[i], w2 = a2[i], w3 = a3[i];
        acc0 += xv;
        acc1 = fmaf(w1, xv, acc1);
        acc2 = fmaf(w2, xv, acc2);
        acc3 = fmaf(w3, xv, acc3);
        if (col == 0) { ss1 += w1; ss2 += w2; }
    }
    __shared__ float sm[4][4][64];
    __shared__ float sms[2][4];
    sm[0][rg][col] = acc0; sm[1][rg][col] = acc1;
    sm[2][rg][col] = acc2; sm[3][rg][col] = acc3;
    if (col == 0) { sms[0][rg] = ss1; sms[1][rg] = ss2; }
    __syncthreads();
    if (rg == 0) {
        #pragma unroll
        for (int k = 0; k < 4; k++) {
            float v = sm[k][0][col] + sm[k][1][col] + sm[k][2][col] + sm[k][3][col];
            atomicAdd(&X[k * D + col], v);
        }
        if (col == 0) atomicAdd(&X[4 * D],     sms[0][0] + sms[0][1] + sms[0][2] + sms[0][3]);
        if (col == 1) atomicAdd(&X[4 * D + 1], sms[1][0] + sms[1][1] + sms[1][2] + sms[1][3]);
    }
}

// Chain of 64x64 matvecs; 1 block, 64 threads (one wave).
__global__ void final_kernel(const float* __restrict__ X,
    const float* __restrict__ Wl1, const float* __restrict__ bl1, const float* __restrict__ Wr1,
    const float* __restrict__ Wl2, const float* __restrict__ bl2, const float* __restrict__ Wr2,
    const float* __restrict__ Wl3, const float* __restrict__ bl3, const float* __restrict__ Wr3,
    const float* __restrict__ Wlin, const float* __restrict__ blin,
    float* __restrict__ out, int nn) {
    const int t = threadIdx.x;  // 0..63
    __shared__ float X1[D], X2[D], X3[D], X4[D];
    __shared__ float m1u[D], m1a1[D], m1a2[D], m2u[D], m2a1[D];
    const float invN = 1.0f / (float)nn;
    X1[t] = X[t] * invN;
    X2[t] = X[D + t];
    X3[t] = X[2 * D + t];
    X4[t] = X[3 * D + t];
    const float s1 = X[4 * D], s2 = X[4 * D + 1];
    __syncthreads();

    // m1(v) = h1^T v:  m1u = Wl1*X2 + bl1 + Wr1*X1 ; m1a1 = Wl1*X3 + bl1*s1 + Wr1*X2 ;
    //                  m1a2 = Wl1*X4 + bl1*s2 + Wr1*X3
    float dl2 = 0.f, dl3 = 0.f, dl4 = 0.f, dr1 = 0.f, dr2 = 0.f, dr3 = 0.f;
    for (int c = 0; c < D; c++) {
        float wl = Wl1[t * D + c], wr = Wr1[t * D + c];
        dl2 = fmaf(wl, X2[c], dl2);
        dl3 = fmaf(wl, X3[c], dl3);
        dl4 = fmaf(wl, X4[c], dl4);
        dr1 = fmaf(wr, X1[c], dr1);
        dr2 = fmaf(wr, X2[c], dr2);
        dr3 = fmaf(wr, X3[c], dr3);
    }
    m1u[t]  = dl2 + bl1[t]      + dr1;
    m1a1[t] = dl3 + bl1[t] * s1 + dr2;
    m1a2[t] = dl4 + bl1[t] * s2 + dr3;
    __syncthreads();

    // m2u = Wl2*m1a1 + bl2 + Wr2*m1u ; m2a1 = Wl2*m1a2 + bl2*s1 + Wr2*m1a1
    float el1 = 0.f, el2 = 0.f, er0 = 0.f, er1 = 0.f;
    for (int c = 0; c < D; c++) {
        float wl = Wl2[t * D + c], wr = Wr2[t * D + c];
        el1 = fmaf(wl, m1a1[c], el1);
        el2 = fmaf(wl, m1a2[c], el2);
        er0 = fmaf(wr, m1u[c],  er0);
        er1 = fmaf(wr, m1a1[c], er1);
    }
    m2u[t]  = el1 + bl2[t]      + er0;
    m2a1[t] = el2 + bl2[t] * s1 + er1;
    __syncthreads();

    // h3^T u = Wl3*m2a1 + bl3 + Wr3*m2u ; out = wlin . (h3^T u) + blin
    float fl = 0.f, fr = 0.f;
    for (int c = 0; c < D; c++) {
        fl = fmaf(Wl3[t * D + c], m2a1[c], fl);
        fr = fmaf(Wr3[t * D + c], m2u[c],  fr);
    }
    float h3 = fl + bl3[t] + fr;
    float val = Wlin[t] * h3;
    #pragma unroll
    for (int off = 32; off; off >>= 1) val += __shfl_down(val, off);
    if (t == 0) out[0] = val + blin[0];
}

extern "C" void kernel_launch(void* const* d_in, const int* in_sizes, int n_in,
                              void* d_out, int out_size, void* d_ws, size_t ws_size,
                              hipStream_t stream) {
    const float* x    = (const float*)d_in[0];
    const int*   ei   = (const int*)d_in[1];
    const float* Wl1  = (const float*)d_in[2];
    const float* bl1  = (const float*)d_in[3];
    const float* Wr1  = (const float*)d_in[4];
    const float* Wl2  = (const float*)d_in[5];
    const float* bl2  = (const float*)d_in[6];
    const float* Wr2  = (const float*)d_in[7];
    const float* Wl3  = (const float*)d_in[8];
    const float* bl3  = (const float*)d_in[9];
    const float* Wr3  = (const float*)d_in[10];
    const float* Wlin = (const float*)d_in[11];
    const float* blin = (const float*)d_in[12];
    float* out = (float*)d_out;

    const int nn = in_sizes[0] / D;        // 100000
    const int ne = in_sizes[1] / 2;        // 3200000
    const int* srcIdx = ei;                // edge_index[0]
    const int* dstIdx = ei + ne;           // edge_index[1]

    float* ws  = (float*)d_ws;
    float* cnt = ws;
    float* a1  = ws + (size_t)nn;
    float* a2  = ws + (size_t)2 * nn;
    float* a3  = ws + (size_t)3 * nn;
    float* r   = ws + (size_t)4 * nn;
    float* X   = ws + (size_t)5 * nn;      // 4*64 + 2 floats

    const int B = 256;
    const int zn = 5 * nn + 4 * D + 2;     // zero cnt,a1..a3,r,X
    hipLaunchKernelGGL(zero_kernel, dim3((zn + B - 1) / B), dim3(B), 0, stream, ws, zn);
    hipLaunchKernelGGL(cnt_kernel,  dim3((ne + B - 1) / B), dim3(B), 0, stream, dstIdx, cnt, ne);
    hipLaunchKernelGGL(r0_kernel,   dim3((nn + B - 1) / B), dim3(B), 0, stream, cnt, r, nn);
    hipLaunchKernelGGL(scatter_kernel, dim3((ne + B - 1) / B), dim3(B), 0, stream, srcIdx, dstIdx, r, a1, ne);
    hipLaunchKernelGGL(rdiv_kernel, dim3((nn + B - 1) / B), dim3(B), 0, stream, a1, cnt, r, nn);
    hipLaunchKernelGGL(scatter_kernel, dim3((ne + B - 1) / B), dim3(B), 0, stream, srcIdx, dstIdx, r, a2, ne);
    hipLaunchKernelGGL(rdiv_kernel, dim3((nn + B - 1) / B), dim3(B), 0, stream, a2, cnt, r, nn);
    hipLaunchKernelGGL(scatter_kernel, dim3((ne + B - 1) / B), dim3(B), 0, stream, srcIdx, dstIdx, r, a3, ne);
    hipLaunchKernelGGL(xpass_kernel, dim3(1024), dim3(B), 0, stream, x, a1, a2, a3, X, nn);
    hipLaunchKernelGGL(final_kernel, dim3(1), dim3(64), 0, stream, X,
                       Wl1, bl1, Wr1, Wl2, bl2, Wr2, Wl3, bl3, Wr3, Wlin, blin, out, nn);
}

// Round 2
// 251.723 us; speedup vs baseline: 2.8700x; 2.8700x over previous
//
#include <hip/hip_runtime.h>
#include <stdint.h>

#define D 64
#define NBLK 512      // blocks for hist/place passes
#define NBMAX 512     // max buckets supported (nb = ceil(nn/256) = 391)

// ---------------- zero ----------------
__global__ void zero_kernel(float* __restrict__ p, int n) {
    int i = blockIdx.x * blockDim.x + threadIdx.x;
    if (i < n) p[i] = 0.0f;
}

// =====================================================================
// Fallback path (global-atomic version) — used only if ws too small
// =====================================================================
__global__ void cnt_kernel(const int* __restrict__ dst, float* __restrict__ cnt, int ne) {
    int i = blockIdx.x * blockDim.x + threadIdx.x;
    if (i < ne) atomicAdd(&cnt[dst[i]], 1.0f);
}
__global__ void scatter_kernel(const int* __restrict__ src, const int* __restrict__ dst,
                               const float* __restrict__ r, float* __restrict__ an, int ne) {
    int i = blockIdx.x * blockDim.x + threadIdx.x;
    if (i < ne) atomicAdd(&an[src[i]], r[dst[i]]);
}

// =====================================================================
// Bucketed path
// =====================================================================

// Phase 1: per-block LDS histograms of src-bucket and dst-bucket.
__global__ void hist_kernel(const int* __restrict__ src, const int* __restrict__ dst,
                            uint32_t* __restrict__ blkhistS, uint32_t* __restrict__ blkhistD,
                            int ne, int nb, int chunk) {
    __shared__ uint32_t hS[NBMAX], hD[NBMAX];
    for (int i = threadIdx.x; i < nb; i += blockDim.x) { hS[i] = 0u; hD[i] = 0u; }
    __syncthreads();
    int beg = blockIdx.x * chunk;
    int end = min(beg + chunk, ne);
    for (int e = beg + threadIdx.x; e < end; e += blockDim.x) {
        atomicAdd(&hS[((uint32_t)src[e]) >> 8], 1u);
        atomicAdd(&hD[((uint32_t)dst[e]) >> 8], 1u);
    }
    __syncthreads();
    for (int i = threadIdx.x; i < nb; i += blockDim.x) {
        blkhistS[(size_t)blockIdx.x * nb + i] = hS[i];
        blkhistD[(size_t)blockIdx.x * nb + i] = hD[i];
    }
}

// Phase 2a: bucket totals + exclusive scan -> bucket start offsets. grid=2.
__global__ void binsum_kernel(const uint32_t* __restrict__ blkhistS,
                              const uint32_t* __restrict__ blkhistD,
                              uint32_t* __restrict__ bstartS, uint32_t* __restrict__ bstartD,
                              int nb) {
    const uint32_t* bh = blockIdx.x ? blkhistD : blkhistS;
    uint32_t* bs       = blockIdx.x ? bstartD  : bstartS;
    __shared__ uint32_t tot[NBMAX];
    for (int b = threadIdx.x; b < nb; b += blockDim.x) {
        uint32_t s = 0;
        for (int blk = 0; blk < NBLK; blk++) s += bh[(size_t)blk * nb + b];
        tot[b] = s;
    }
    __syncthreads();
    if (threadIdx.x == 0) {
        uint32_t run = 0;
        for (int b = 0; b < nb; b++) { uint32_t c = tot[b]; bs[b] = run; run += c; }
        bs[nb] = run;
    }
}

// Phase 2b: per-(block,bucket) exclusive offsets. grid = 2*nb blocks, 64 threads.
__global__ void offsets_kernel(const uint32_t* __restrict__ blkhistS,
                               const uint32_t* __restrict__ blkhistD,
                               const uint32_t* __restrict__ bstartS,
                               const uint32_t* __restrict__ bstartD,
                               uint32_t* __restrict__ offsS, uint32_t* __restrict__ offsD,
                               int nb) {
    int which = (blockIdx.x >= nb) ? 1 : 0;
    int b = blockIdx.x - which * nb;
    const uint32_t* bh = which ? blkhistD : blkhistS;
    const uint32_t* bs = which ? bstartD  : bstartS;
    uint32_t* of       = which ? offsD    : offsS;
    int lane = threadIdx.x;           // 64 threads, 8 blks each
    uint32_t v[8];
    uint32_t s = 0;
    int base = lane * 8;
    #pragma unroll
    for (int k = 0; k < 8; k++) { v[k] = bh[(size_t)(base + k) * nb + b]; s += v[k]; }
    uint32_t inc = s;
    #pragma unroll
    for (int off = 1; off < 64; off <<= 1) {
        uint32_t n = __shfl_up(inc, off, 64);
        if (lane >= off) inc += n;
    }
    uint32_t run = bs[b] + (inc - s);  // exclusive prefix across blocks
    #pragma unroll
    for (int k = 0; k < 8; k++) { of[(size_t)(base + k) * nb + b] = run; run += v[k]; }
}

// Phase 3: place packed edge records into bucket-grouped arrays.
// sortedS[e] = (src&255)<<17 | dst   (grouped by src>>8)
// sortedD[e] = (uint8)(dst&255)      (grouped by dst>>8)
__global__ void place_kernel(const int* __restrict__ src, const int* __restrict__ dst,
                             const uint32_t* __restrict__ offsS, const uint32_t* __restrict__ offsD,
                             uint32_t* __restrict__ sortedS, uint8_t* __restrict__ sortedD,
                             int ne, int nb, int chunk) {
    __shared__ uint32_t oS[NBMAX], oD[NBMAX];
    for (int i = threadIdx.x; i < nb; i += blockDim.x) {
        oS[i] = offsS[(size_t)blockIdx.x * nb + i];
        oD[i] = offsD[(size_t)blockIdx.x * nb + i];
    }
    __syncthreads();
    int beg = blockIdx.x * chunk;
    int end = min(beg + chunk, ne);
    for (int e = beg + threadIdx.x; e < end; e += blockDim.x) {
        uint32_t sv = (uint32_t)src[e], dv = (uint32_t)dst[e];
        uint32_t pS = atomicAdd(&oS[sv >> 8], 1u);
        sortedS[pS] = ((sv & 255u) << 17) | dv;
        uint32_t pD = atomicAdd(&oD[dv >> 8], 1u);
        sortedD[pD] = (uint8_t)(dv & 255u);
    }
}

// In-degree via dst-bucketed bytes; block owns 256 nodes -> non-atomic write.
__global__ void cntb_kernel(const uint8_t* __restrict__ sortedD,
                            const uint32_t* __restrict__ bstartD,
                            float* __restrict__ cnt, int nn) {
    int b = blockIdx.x;
    __shared__ uint32_t c[256];
    c[threadIdx.x] = 0u;
    __syncthreads();
    uint32_t beg = bstartD[b], end = bstartD[b + 1];
    for (uint32_t e = beg + threadIdx.x; e < end; e += blockDim.x)
        atomicAdd(&c[sortedD[e]], 1u);
    __syncthreads();
    int v = b * 256 + threadIdx.x;
    if (v < nn) cnt[v] = (float)c[threadIdx.x];
}

// a_next[v] = sum_{e: src=v} r[dst[e]] — LDS accumulate, exclusive write.
__global__ void scatb_kernel(const uint32_t* __restrict__ sortedS,
                             const uint32_t* __restrict__ bstartS,
                             const float* __restrict__ r, float* __restrict__ an, int nn) {
    int b = blockIdx.x;
    __shared__ float acc[256];
    acc[threadIdx.x] = 0.0f;
    __syncthreads();
    uint32_t beg = bstartS[b], end = bstartS[b + 1];
    for (uint32_t e = beg + threadIdx.x; e < end; e += blockDim.x) {
        uint32_t p = sortedS[e];
        atomicAdd(&acc[p >> 17], r[p & 0x1FFFFu]);
    }
    __syncthreads();
    int v = b * 256 + threadIdx.x;
    if (v < nn) an[v] = acc[threadIdx.x];
}

// ---------------- shared small kernels ----------------
__global__ void r0_kernel(const float* __restrict__ cnt, float* __restrict__ r, int nn) {
    int i = blockIdx.x * blockDim.x + threadIdx.x;
    if (i < nn) {
        float c = fmaxf(cnt[i], 1.0f);
        r[i] = (1.0f / (float)nn) / c;
    }
}
__global__ void rdiv_kernel(const float* __restrict__ a, const float* __restrict__ cnt,
                            float* __restrict__ r, int nn) {
    int i = blockIdx.x * blockDim.x + threadIdx.x;
    if (i < nn) {
        float c = fmaxf(cnt[i], 1.0f);
        r[i] = a[i] / c;
    }
}

__global__ void xpass_kernel(const float* __restrict__ x,
                             const float* __restrict__ a1, const float* __restrict__ a2,
                             const float* __restrict__ a3, float* __restrict__ X, int nn) {
    int col = threadIdx.x & 63;
    int rg  = threadIdx.x >> 6;   // 0..3
    float acc0 = 0.f, acc1 = 0.f, acc2 = 0.f, acc3 = 0.f, ss1 = 0.f, ss2 = 0.f;
    for (int i = blockIdx.x * 4 + rg; i < nn; i += gridDim.x * 4) {
        float xv = x[i * D + col];
        float w1 = a1[i], w2 = a2[i], w3 = a3[i];
        acc0 += xv;
        acc1 = fmaf(w1, xv, acc1);
        acc2 = fmaf(w2, xv, acc2);
        acc3 = fmaf(w3, xv, acc3);
        if (col == 0) { ss1 += w1; ss2 += w2; }
    }
    __shared__ float sm[4][4][64];
    __shared__ float sms[2][4];
    sm[0][rg][col] = acc0; sm[1][rg][col] = acc1;
    sm[2][rg][col] = acc2; sm[3][rg][col] = acc3;
    if (col == 0) { sms[0][rg] = ss1; sms[1][rg] = ss2; }
    __syncthreads();
    if (rg == 0) {
        #pragma unroll
        for (int k = 0; k < 4; k++) {
            float v = sm[k][0][col] + sm[k][1][col] + sm[k][2][col] + sm[k][3][col];
            atomicAdd(&X[k * D + col], v);
        }
        if (col == 0) atomicAdd(&X[4 * D],     sms[0][0] + sms[0][1] + sms[0][2] + sms[0][3]);
        if (col == 1) atomicAdd(&X[4 * D + 1], sms[1][0] + sms[1][1] + sms[1][2] + sms[1][3]);
    }
}

// Chain of 64x64 matvecs; 1 block, 64 threads (one wave).
__global__ void final_kernel(const float* __restrict__ X,
    const float* __restrict__ Wl1, const float* __restrict__ bl1, const float* __restrict__ Wr1,
    const float* __restrict__ Wl2, const float* __restrict__ bl2, const float* __restrict__ Wr2,
    const float* __restrict__ Wl3, const float* __restrict__ bl3, const float* __restrict__ Wr3,
    const float* __restrict__ Wlin, const float* __restrict__ blin,
    float* __restrict__ out, int nn) {
    const int t = threadIdx.x;  // 0..63
    __shared__ float X1[D], X2[D], X3[D], X4[D];
    __shared__ float m1u[D], m1a1[D], m1a2[D], m2u[D], m2a1[D];
    const float invN = 1.0f / (float)nn;
    X1[t] = X[t] * invN;
    X2[t] = X[D + t];
    X3[t] = X[2 * D + t];
    X4[t] = X[3 * D + t];
    const float s1 = X[4 * D], s2 = X[4 * D + 1];
    __syncthreads();

    float dl2 = 0.f, dl3 = 0.f, dl4 = 0.f, dr1 = 0.f, dr2 = 0.f, dr3 = 0.f;
    for (int c = 0; c < D; c++) {
        float wl = Wl1[t * D + c], wr = Wr1[t * D + c];
        dl2 = fmaf(wl, X2[c], dl2);
        dl3 = fmaf(wl, X3[c], dl3);
        dl4 = fmaf(wl, X4[c], dl4);
        dr1 = fmaf(wr, X1[c], dr1);
        dr2 = fmaf(wr, X2[c], dr2);
        dr3 = fmaf(wr, X3[c], dr3);
    }
    m1u[t]  = dl2 + bl1[t]      + dr1;
    m1a1[t] = dl3 + bl1[t] * s1 + dr2;
    m1a2[t] = dl4 + bl1[t] * s2 + dr3;
    __syncthreads();

    float el1 = 0.f, el2 = 0.f, er0 = 0.f, er1 = 0.f;
    for (int c = 0; c < D; c++) {
        float wl = Wl2[t * D + c], wr = Wr2[t * D + c];
        el1 = fmaf(wl, m1a1[c], el1);
        el2 = fmaf(wl, m1a2[c], el2);
        er0 = fmaf(wr, m1u[c],  er0);
        er1 = fmaf(wr, m1a1[c], er1);
    }
    m2u[t]  = el1 + bl2[t]      + er0;
    m2a1[t] = el2 + bl2[t] * s1 + er1;
    __syncthreads();

    float fl = 0.f, fr = 0.f;
    for (int c = 0; c < D; c++) {
        fl = fmaf(Wl3[t * D + c], m2a1[c], fl);
        fr = fmaf(Wr3[t * D + c], m2u[c],  fr);
    }
    float h3 = fl + bl3[t] + fr;
    float val = Wlin[t] * h3;
    #pragma unroll
    for (int off = 32; off; off >>= 1) val += __shfl_down(val, off);
    if (t == 0) out[0] = val + blin[0];
}

extern "C" void kernel_launch(void* const* d_in, const int* in_sizes, int n_in,
                              void* d_out, int out_size, void* d_ws, size_t ws_size,
                              hipStream_t stream) {
    const float* x    = (const float*)d_in[0];
    const int*   ei   = (const int*)d_in[1];
    const float* Wl1  = (const float*)d_in[2];
    const float* bl1  = (const float*)d_in[3];
    const float* Wr1  = (const float*)d_in[4];
    const float* Wl2  = (const float*)d_in[5];
    const float* bl2  = (const float*)d_in[6];
    const float* Wr2  = (const float*)d_in[7];
    const float* Wl3  = (const float*)d_in[8];
    const float* bl3  = (const float*)d_in[9];
    const float* Wr3  = (const float*)d_in[10];
    const float* Wlin = (const float*)d_in[11];
    const float* blin = (const float*)d_in[12];
    float* out = (float*)d_out;

    const int nn = in_sizes[0] / D;        // 100000
    const int ne = in_sizes[1] / 2;        // 3200000
    const int* srcIdx = ei;                // edge_index[0]
    const int* dstIdx = ei + ne;           // edge_index[1]
    const int nb = (nn + 255) >> 8;        // 391 buckets of 256 nodes

    // ---- workspace layout (256B-aligned chunks) ----
    char* base = (char*)d_ws;
    size_t cur = 0;
    auto alloc = [&](size_t bytes) -> void* {
        void* p = base + cur;
        cur = (cur + bytes + 255) & ~(size_t)255;
        return p;
    };
    float*    cnt      = (float*)alloc((size_t)nn * 4);
    float*    a1       = (float*)alloc((size_t)nn * 4);
    float*    a2       = (float*)alloc((size_t)nn * 4);
    float*    a3       = (float*)alloc((size_t)nn * 4);
    float*    r        = (float*)alloc((size_t)nn * 4);
    float*    X        = (float*)alloc((4 * D + 2) * 4);
    uint32_t* blkhistS = (uint32_t*)alloc((size_t)NBLK * nb * 4);
    uint32_t* blkhistD = (uint32_t*)alloc((size_t)NBLK * nb * 4);
    uint32_t* offsS    = (uint32_t*)alloc((size_t)NBLK * nb * 4);
    uint32_t* offsD    = (uint32_t*)alloc((size_t)NBLK * nb * 4);
    uint32_t* bstartS  = (uint32_t*)alloc((size_t)(nb + 1) * 4);
    uint32_t* bstartD  = (uint32_t*)alloc((size_t)(nb + 1) * 4);
    uint32_t* sortedS  = (uint32_t*)alloc((size_t)ne * 4);
    uint8_t*  sortedD  = (uint8_t*)alloc((size_t)ne);
    const size_t need = cur;

    const int B = 256;
    if (need <= ws_size && nn <= 131071 && nb <= NBMAX) {
        // ================= bucketed path =================
        const int chunk = (ne + NBLK - 1) / NBLK;
        hipLaunchKernelGGL(zero_kernel, dim3(1), dim3(B), 0, stream, X, 4 * D + 2);
        hipLaunchKernelGGL(hist_kernel, dim3(NBLK), dim3(B), 0, stream,
                           srcIdx, dstIdx, blkhistS, blkhistD, ne, nb, chunk);
        hipLaunchKernelGGL(binsum_kernel, dim3(2), dim3(512), 0, stream,
                           blkhistS, blkhistD, bstartS, bstartD, nb);
        hipLaunchKernelGGL(offsets_kernel, dim3(2 * nb), dim3(64), 0, stream,
                           blkhistS, blkhistD, bstartS, bstartD, offsS, offsD, nb);
        hipLaunchKernelGGL(place_kernel, dim3(NBLK), dim3(B), 0, stream,
                           srcIdx, dstIdx, offsS, offsD, sortedS, sortedD, ne, nb, chunk);
        hipLaunchKernelGGL(cntb_kernel, dim3(nb), dim3(B), 0, stream, sortedD, bstartD, cnt, nn);
        hipLaunchKernelGGL(r0_kernel, dim3((nn + B - 1) / B), dim3(B), 0, stream, cnt, r, nn);
        hipLaunchKernelGGL(scatb_kernel, dim3(nb), dim3(B), 0, stream, sortedS, bstartS, r, a1, nn);
        hipLaunchKernelGGL(rdiv_kernel, dim3((nn + B - 1) / B), dim3(B), 0, stream, a1, cnt, r, nn);
        hipLaunchKernelGGL(scatb_kernel, dim3(nb), dim3(B), 0, stream, sortedS, bstartS, r, a2, nn);
        hipLaunchKernelGGL(rdiv_kernel, dim3((nn + B - 1) / B), dim3(B), 0, stream, a2, cnt, r, nn);
        hipLaunchKernelGGL(scatb_kernel, dim3(nb), dim3(B), 0, stream, sortedS, bstartS, r, a3, nn);
    } else {
        // ================= fallback: global-atomic path =================
        const int zn = 5 * nn + 4 * D + 2;
        hipLaunchKernelGGL(zero_kernel, dim3((zn + B - 1) / B), dim3(B), 0, stream, (float*)d_ws, zn);
        hipLaunchKernelGGL(cnt_kernel,  dim3((ne + B - 1) / B), dim3(B), 0, stream, dstIdx, cnt, ne);
        hipLaunchKernelGGL(r0_kernel,   dim3((nn + B - 1) / B), dim3(B), 0, stream, cnt, r, nn);
        hipLaunchKernelGGL(scatter_kernel, dim3((ne + B - 1) / B), dim3(B), 0, stream, srcIdx, dstIdx, r, a1, ne);
        hipLaunchKernelGGL(rdiv_kernel, dim3((nn + B - 1) / B), dim3(B), 0, stream, a1, cnt, r, nn);
        hipLaunchKernelGGL(scatter_kernel, dim3((ne + B - 1) / B), dim3(B), 0, stream, srcIdx, dstIdx, r, a2, ne);
        hipLaunchKernelGGL(rdiv_kernel, dim3((nn + B - 1) / B), dim3(B), 0, stream, a2, cnt, r, nn);
        hipLaunchKernelGGL(scatter_kernel, dim3((ne + B - 1) / B), dim3(B), 0, stream, srcIdx, dstIdx, r, a3, ne);
    }

    hipLaunchKernelGGL(xpass_kernel, dim3(1024), dim3(B), 0, stream, x, a1, a2, a3, X, nn);
    hipLaunchKernelGGL(final_kernel, dim3(1), dim3(64), 0, stream, X,
                       Wl1, bl1, Wr1, Wl2, bl2, Wr2, Wl3, bl3, Wr3, Wlin, blin, out, nn);
}

// Round 3
// 195.072 us; speedup vs baseline: 3.7035x; 1.2904x over previous
//
#include <hip/hip_runtime.h>
#include <stdint.h>

#define D 64
#define PNBLK 256     // blocks for hist/place passes
#define NBMAX 400     // max buckets (nb = ceil(nn/256) = 391)
#define CAPS 16       // staging entries per bucket (one 64B line)

// ---------------- zero (fallback + X) ----------------
__global__ void zero_kernel(float* __restrict__ p, int n) {
    int i = blockIdx.x * blockDim.x + threadIdx.x;
    if (i < n) p[i] = 0.0f;
}

// =====================================================================
// Fallback path (global-atomic) — used only if ws too small
// =====================================================================
__global__ void cnt_kernel(const int* __restrict__ dst, float* __restrict__ cnt, int ne) {
    int i = blockIdx.x * blockDim.x + threadIdx.x;
    if (i < ne) atomicAdd(&cnt[dst[i]], 1.0f);
}
__global__ void scatter_kernel(const int* __restrict__ src, const int* __restrict__ dst,
                               const float* __restrict__ r, float* __restrict__ an, int ne) {
    int i = blockIdx.x * blockDim.x + threadIdx.x;
    if (i < ne) atomicAdd(&an[src[i]], r[dst[i]]);
}
__global__ void r0_kernel(const float* __restrict__ cnt, float* __restrict__ r, int nn) {
    int i = blockIdx.x * blockDim.x + threadIdx.x;
    if (i < nn) r[i] = (1.0f / (float)nn) / fmaxf(cnt[i], 1.0f);
}
__global__ void rdiv_kernel(const float* __restrict__ a, const float* __restrict__ cnt,
                            float* __restrict__ r, int nn) {
    int i = blockIdx.x * blockDim.x + threadIdx.x;
    if (i < nn) r[i] = a[i] / fmaxf(cnt[i], 1.0f);
}

// =====================================================================
// Bucketed path
// =====================================================================

// Phase 1: per-block histograms of src-bucket and dst-bucket (int4 loads).
__global__ __launch_bounds__(512) void hist_kernel(
        const int* __restrict__ src, const int* __restrict__ dst,
        uint32_t* __restrict__ blkhistS, uint32_t* __restrict__ blkhistD,
        int ne, int nb, int chunk) {
    __shared__ uint32_t hS[NBMAX], hD[NBMAX];
    const int T = blockDim.x, tid = threadIdx.x;
    for (int i = tid; i < nb; i += T) { hS[i] = 0u; hD[i] = 0u; }
    __syncthreads();
    int beg = blockIdx.x * chunk;
    int end = min(beg + chunk, ne);
    for (int base = beg; base < end; base += T * 4) {
        int e0 = base + tid * 4;
        if (e0 + 3 < end) {
            int4 s4 = *(const int4*)(src + e0);
            int4 d4 = *(const int4*)(dst + e0);
            atomicAdd(&hS[((uint32_t)s4.x) >> 8], 1u);
            atomicAdd(&hS[((uint32_t)s4.y) >> 8], 1u);
            atomicAdd(&hS[((uint32_t)s4.z) >> 8], 1u);
            atomicAdd(&hS[((uint32_t)s4.w) >> 8], 1u);
            atomicAdd(&hD[((uint32_t)d4.x) >> 8], 1u);
            atomicAdd(&hD[((uint32_t)d4.y) >> 8], 1u);
            atomicAdd(&hD[((uint32_t)d4.z) >> 8], 1u);
            atomicAdd(&hD[((uint32_t)d4.w) >> 8], 1u);
        } else {
            for (int k = 0; k < 4; k++) {
                int e = e0 + k;
                if (e < end) {
                    atomicAdd(&hS[((uint32_t)src[e]) >> 8], 1u);
                    atomicAdd(&hD[((uint32_t)dst[e]) >> 8], 1u);
                }
            }
        }
    }
    __syncthreads();
    for (int i = tid; i < nb; i += T) {
        blkhistS[(size_t)blockIdx.x * nb + i] = hS[i];
        blkhistD[(size_t)blockIdx.x * nb + i] = hD[i];
    }
}

// Phase 2a: bucket totals + parallel exclusive scan. grid=2, T=512. Also zeros X.
__global__ __launch_bounds__(512) void binsum_kernel(
        const uint32_t* __restrict__ blkhistS, const uint32_t* __restrict__ blkhistD,
        uint32_t* __restrict__ bstartS, uint32_t* __restrict__ bstartD,
        float* __restrict__ X, int nb) {
    const uint32_t* bh = blockIdx.x ? blkhistD : blkhistS;
    uint32_t* bs       = blockIdx.x ? bstartD  : bstartS;
    const int tid = threadIdx.x;
    if (blockIdx.x == 0 && tid < 4 * D + 2) X[tid] = 0.0f;
    int b = tid;
    uint32_t tot = 0;
    if (b < nb)
        for (int blk = 0; blk < PNBLK; blk++) tot += bh[(size_t)blk * nb + b];
    // block-wide exclusive scan (wave scan + wave-total scan)
    int lane = tid & 63, wid = tid >> 6;
    uint32_t incl = tot;
    #pragma unroll
    for (int off = 1; off < 64; off <<= 1) {
        uint32_t nbr = __shfl_up(incl, off, 64);
        if (lane >= off) incl += nbr;
    }
    __shared__ uint32_t wsum[8];
    if (lane == 63) wsum[wid] = incl;
    __syncthreads();
    if (wid == 0 && lane < 8) {
        uint32_t w = wsum[lane], wi = w;
        #pragma unroll
        for (int off = 1; off < 8; off <<= 1) {
            uint32_t nbr = __shfl_up(wi, off, 8);
            if (lane >= off) wi += nbr;
        }
        wsum[lane] = wi - w;   // exclusive
    }
    __syncthreads();
    uint32_t excl = incl - tot + wsum[wid];
    if (b < nb) bs[b] = excl;
    if (b == nb - 1) bs[nb] = excl + tot;
}

// Phase 2b: per-(block,bucket) exclusive offsets. grid = 2*nb, 64 threads.
__global__ __launch_bounds__(64) void offsets_kernel(
        const uint32_t* __restrict__ blkhistS, const uint32_t* __restrict__ blkhistD,
        const uint32_t* __restrict__ bstartS, const uint32_t* __restrict__ bstartD,
        uint32_t* __restrict__ offsS, uint32_t* __restrict__ offsD, int nb) {
    int which = (blockIdx.x >= nb) ? 1 : 0;
    int b = blockIdx.x - which * nb;
    const uint32_t* bh = which ? blkhistD : blkhistS;
    const uint32_t* bs = which ? bstartD  : bstartS;
    uint32_t* of       = which ? offsD    : offsS;
    int lane = threadIdx.x;            // 64 threads, PNBLK/64 = 4 blocks each
    const int K = PNBLK / 64;
    uint32_t v[K];
    uint32_t s = 0;
    int base = lane * K;
    #pragma unroll
    for (int k = 0; k < K; k++) { v[k] = bh[(size_t)(base + k) * nb + b]; s += v[k]; }
    uint32_t inc = s;
    #pragma unroll
    for (int off = 1; off < 64; off <<= 1) {
        uint32_t nbr = __shfl_up(inc, off, 64);
        if (lane >= off) inc += nbr;
    }
    uint32_t run = bs[b] + (inc - s);
    #pragma unroll
    for (int k = 0; k < K; k++) { of[(size_t)(base + k) * nb + b] = run; run += v[k]; }
}

// Phase 3: place with LDS write-combining (full 64B-line flushes).
// sortedS[e] = (src&255)<<17 | dst   grouped by src>>8
// sortedD[e] = dst&255               grouped by dst>>8 (dword entries)
__global__ __launch_bounds__(512) void place_kernel(
        const int* __restrict__ src, const int* __restrict__ dst,
        const uint32_t* __restrict__ offsS, const uint32_t* __restrict__ offsD,
        uint32_t* __restrict__ sortedS, uint32_t* __restrict__ sortedD,
        int ne, int nb, int chunk) {
    __shared__ uint32_t stS[NBMAX * CAPS];
    __shared__ uint32_t stD[NBMAX * CAPS];
    __shared__ uint32_t pendS[NBMAX], pendD[NBMAX];
    __shared__ uint32_t gposS[NBMAX], gposD[NBMAX];
    __shared__ int again;
    const int T = blockDim.x, tid = threadIdx.x;
    for (int i = tid; i < nb; i += T) {
        pendS[i] = 0u; pendD[i] = 0u;
        gposS[i] = offsS[(size_t)blockIdx.x * nb + i];
        gposD[i] = offsD[(size_t)blockIdx.x * nb + i];
    }
    __syncthreads();
    int beg = blockIdx.x * chunk;
    int end = min(beg + chunk, ne);
    for (int base = beg; base < end; base += T * 4) {
        uint32_t vS[4], vD[4]; int bS[4], bD[4]; bool hS[4], hD[4];
        int e0 = base + tid * 4;
        if (e0 + 3 < end) {
            int4 s4 = *(const int4*)(src + e0);
            int4 d4 = *(const int4*)(dst + e0);
            int sv[4] = {s4.x, s4.y, s4.z, s4.w};
            int dv[4] = {d4.x, d4.y, d4.z, d4.w};
            #pragma unroll
            for (int k = 0; k < 4; k++) {
                uint32_t s = (uint32_t)sv[k], d = (uint32_t)dv[k];
                bS[k] = s >> 8; vS[k] = ((s & 255u) << 17) | d;
                bD[k] = d >> 8; vD[k] = d & 255u;
                hS[k] = true; hD[k] = true;
            }
        } else {
            #pragma unroll
            for (int k = 0; k < 4; k++) {
                int e = e0 + k;
                bool ok = e < end;
                hS[k] = ok; hD[k] = ok;
                if (ok) {
                    uint32_t s = (uint32_t)src[e], d = (uint32_t)dst[e];
                    bS[k] = s >> 8; vS[k] = ((s & 255u) << 17) | d;
                    bD[k] = d >> 8; vD[k] = d & 255u;
                } else { bS[k] = 0; bD[k] = 0; vS[k] = 0; vD[k] = 0; }
            }
        }
        while (true) {
            if (tid == 0) again = 0;
            __syncthreads();
            #pragma unroll
            for (int k = 0; k < 4; k++) {
                if (hS[k]) {
                    uint32_t p = atomicAdd(&pendS[bS[k]], 1u);
                    if (p < CAPS) { stS[bS[k] * CAPS + p] = vS[k]; hS[k] = false; }
                }
                if (hD[k]) {
                    uint32_t p = atomicAdd(&pendD[bD[k]], 1u);
                    if (p < CAPS) { stD[bD[k] * CAPS + p] = vD[k]; hD[k] = false; }
                }
            }
            if (hS[0] | hS[1] | hS[2] | hS[3] | hD[0] | hD[1] | hD[2] | hD[3]) again = 1;
            __syncthreads();
            for (int bb = tid; bb < nb; bb += T) {
                uint32_t n = min(pendS[bb], (uint32_t)CAPS);
                if (n == CAPS) {
                    uint32_t g = gposS[bb];
                    #pragma unroll
                    for (int k = 0; k < CAPS; k++) sortedS[g + k] = stS[bb * CAPS + k];
                    gposS[bb] = g + CAPS;
                    pendS[bb] = 0u;
                } else pendS[bb] = n;
                n = min(pendD[bb], (uint32_t)CAPS);
                if (n == CAPS) {
                    uint32_t g = gposD[bb];
                    #pragma unroll
                    for (int k = 0; k < CAPS; k++) sortedD[g + k] = stD[bb * CAPS + k];
                    gposD[bb] = g + CAPS;
                    pendD[bb] = 0u;
                } else pendD[bb] = n;
            }
            __syncthreads();
            if (!again) break;
        }
    }
    // final partial flush
    for (int bb = tid; bb < nb; bb += T) {
        uint32_t n = pendS[bb], g = gposS[bb];
        for (uint32_t k = 0; k < n; k++) sortedS[g + k] = stS[bb * CAPS + k];
        n = pendD[bb]; g = gposD[bb];
        for (uint32_t k = 0; k < n; k++) sortedD[g + k] = stD[bb * CAPS + k];
    }
}

// In-degree + r0 fused; block owns 256 nodes.
__global__ __launch_bounds__(256) void cntb_kernel(
        const uint32_t* __restrict__ sortedD, const uint32_t* __restrict__ bstartD,
        float* __restrict__ cnt, float* __restrict__ r, int nn, float invN) {
    int b = blockIdx.x, tid = threadIdx.x;
    __shared__ uint32_t c[256];
    c[tid] = 0u;
    __syncthreads();
    uint32_t beg = bstartD[b], end = bstartD[b + 1];
    for (uint32_t e = beg + tid; e < end; e += 256) atomicAdd(&c[sortedD[e]], 1u);
    __syncthreads();
    int v = b * 256 + tid;
    if (v < nn) {
        float cf = (float)c[tid];
        cnt[v] = cf;
        r[v] = invN / fmaxf(cf, 1.0f);
    }
}

// a_out[v] = sum_{e: src=v} r_in[dst[e]]; r_out[v] = a_out[v]/max(cnt,1) (fused).
__global__ __launch_bounds__(256) void scatb_kernel(
        const uint32_t* __restrict__ sortedS, const uint32_t* __restrict__ bstartS,
        const float* __restrict__ rin, const float* __restrict__ cnt,
        float* __restrict__ aout, float* __restrict__ rout, int nn) {
    int b = blockIdx.x, tid = threadIdx.x;
    __shared__ float acc[256];
    acc[tid] = 0.0f;
    __syncthreads();
    uint32_t beg = bstartS[b], end = bstartS[b + 1];
    for (uint32_t e = beg + tid; e < end; e += 256) {
        uint32_t p = sortedS[e];
        atomicAdd(&acc[p >> 17], rin[p & 0x1FFFFu]);
    }
    __syncthreads();
    int v = b * 256 + tid;
    if (v < nn) {
        float a = acc[tid];
        aout[v] = a;
        if (rout) rout[v] = a / fmaxf(cnt[v], 1.0f);
    }
}

// Weighted column-sums of x.
__global__ __launch_bounds__(256) void xpass_kernel(
        const float* __restrict__ x,
        const float* __restrict__ a1, const float* __restrict__ a2,
        const float* __restrict__ a3, float* __restrict__ X, int nn) {
    int col = threadIdx.x & 63;
    int rg  = threadIdx.x >> 6;   // 0..3
    float acc0 = 0.f, acc1 = 0.f, acc2 = 0.f, acc3 = 0.f, ss1 = 0.f, ss2 = 0.f;
    for (int i = blockIdx.x * 4 + rg; i < nn; i += gridDim.x * 4) {
        float xv = x[i * D + col];
        float w1 = a1[i], w2 = a2[i], w3 = a3[i];
        acc0 += xv;
        acc1 = fmaf(w1, xv, acc1);
        acc2 = fmaf(w2, xv, acc2);
        acc3 = fmaf(w3, xv, acc3);
        if (col == 0) { ss1 += w1; ss2 += w2; }
    }
    __shared__ float sm[4][4][64];
    __shared__ float sms[2][4];
    sm[0][rg][col] = acc0; sm[1][rg][col] = acc1;
    sm[2][rg][col] = acc2; sm[3][rg][col] = acc3;
    if (col == 0) { sms[0][rg] = ss1; sms[1][rg] = ss2; }
    __syncthreads();
    if (rg == 0) {
        #pragma unroll
        for (int k = 0; k < 4; k++) {
            float v = sm[k][0][col] + sm[k][1][col] + sm[k][2][col] + sm[k][3][col];
            atomicAdd(&X[k * D + col], v);
        }
        if (col == 0) atomicAdd(&X[4 * D],     sms[0][0] + sms[0][1] + sms[0][2] + sms[0][3]);
        if (col == 1) atomicAdd(&X[4 * D + 1], sms[1][0] + sms[1][1] + sms[1][2] + sms[1][3]);
    }
}

// Chain of 64x64 matvecs; 256 threads: t=tid>>2 output row, q=tid&3 quarter of c.
__global__ __launch_bounds__(256) void final_kernel(const float* __restrict__ X,
    const float* __restrict__ Wl1, const float* __restrict__ bl1, const float* __restrict__ Wr1,
    const float* __restrict__ Wl2, const float* __restrict__ bl2, const float* __restrict__ Wr2,
    const float* __restrict__ Wl3, const float* __restrict__ bl3, const float* __restrict__ Wr3,
    const float* __restrict__ Wlin, const float* __restrict__ blin,
    float* __restrict__ out, int nn) {
    const int tid = threadIdx.x;
    const int t = tid >> 2, q = tid & 3, c0 = q * 16;
    __shared__ float X1[D], X2[D], X3[D], X4[D];
    __shared__ float m1u[D], m1a1[D], m1a2[D], m2u[D], m2a1[D];
    __shared__ float sred[4];
    if (tid < 64)       X1[tid]       = X[tid] * (1.0f / (float)nn);
    else if (tid < 128) X2[tid - 64]  = X[tid];
    else if (tid < 192) X3[tid - 128] = X[tid];
    else                X4[tid - 192] = X[tid];
    const float s1 = X[4 * D], s2 = X[4 * D + 1];
    __syncthreads();

    float dl2 = 0.f, dl3 = 0.f, dl4 = 0.f, dr1 = 0.f, dr2 = 0.f, dr3 = 0.f;
    #pragma unroll
    for (int k = 0; k < 16; k++) {
        int c = c0 + k;
        float wl = Wl1[t * D + c], wr = Wr1[t * D + c];
        dl2 = fmaf(wl, X2[c], dl2); dl3 = fmaf(wl, X3[c], dl3); dl4 = fmaf(wl, X4[c], dl4);
        dr1 = fmaf(wr, X1[c], dr1); dr2 = fmaf(wr, X2[c], dr2); dr3 = fmaf(wr, X3[c], dr3);
    }
    #define RED4(v) { v += __shfl_down(v, 2, 4); v += __shfl_down(v, 1, 4); }
    RED4(dl2) RED4(dl3) RED4(dl4) RED4(dr1) RED4(dr2) RED4(dr3)
    if (q == 0) {
        m1u[t]  = dl2 + bl1[t]      + dr1;
        m1a1[t] = dl3 + bl1[t] * s1 + dr2;
        m1a2[t] = dl4 + bl1[t] * s2 + dr3;
    }
    __syncthreads();

    float el1 = 0.f, el2 = 0.f, er0 = 0.f, er1 = 0.f;
    #pragma unroll
    for (int k = 0; k < 16; k++) {
        int c = c0 + k;
        float wl = Wl2[t * D + c], wr = Wr2[t * D + c];
        el1 = fmaf(wl, m1a1[c], el1); el2 = fmaf(wl, m1a2[c], el2);
        er0 = fmaf(wr, m1u[c],  er0); er1 = fmaf(wr, m1a1[c], er1);
    }
    RED4(el1) RED4(el2) RED4(er0) RED4(er1)
    if (q == 0) {
        m2u[t]  = el1 + bl2[t]      + er0;
        m2a1[t] = el2 + bl2[t] * s1 + er1;
    }
    __syncthreads();

    float fl = 0.f, fr = 0.f;
    #pragma unroll
    for (int k = 0; k < 16; k++) {
        int c = c0 + k;
        fl = fmaf(Wl3[t * D + c], m2a1[c], fl);
        fr = fmaf(Wr3[t * D + c], m2u[c],  fr);
    }
    RED4(fl) RED4(fr)
    float contrib = 0.f;
    if (q == 0) contrib = Wlin[t] * (fl + bl3[t] + fr);
    #pragma unroll
    for (int off = 32; off; off >>= 1) contrib += __shfl_down(contrib, off);
    if ((tid & 63) == 0) sred[tid >> 6] = contrib;
    __syncthreads();
    if (tid == 0) out[0] = sred[0] + sred[1] + sred[2] + sred[3] + blin[0];
}

extern "C" void kernel_launch(void* const* d_in, const int* in_sizes, int n_in,
                              void* d_out, int out_size, void* d_ws, size_t ws_size,
                              hipStream_t stream) {
    const float* x    = (const float*)d_in[0];
    const int*   ei   = (const int*)d_in[1];
    const float* Wl1  = (const float*)d_in[2];
    const float* bl1  = (const float*)d_in[3];
    const float* Wr1  = (const float*)d_in[4];
    const float* Wl2  = (const float*)d_in[5];
    const float* bl2  = (const float*)d_in[6];
    const float* Wr2  = (const float*)d_in[7];
    const float* Wl3  = (const float*)d_in[8];
    const float* bl3  = (const float*)d_in[9];
    const float* Wr3  = (const float*)d_in[10];
    const float* Wlin = (const float*)d_in[11];
    const float* blin = (const float*)d_in[12];
    float* out = (float*)d_out;

    const int nn = in_sizes[0] / D;        // 100000
    const int ne = in_sizes[1] / 2;        // 3200000
    const int* srcIdx = ei;
    const int* dstIdx = ei + ne;
    const int nb = (nn + 255) >> 8;        // 391

    char* base = (char*)d_ws;
    size_t cur = 0;
    auto alloc = [&](size_t bytes) -> void* {
        void* p = base + cur;
        cur = (cur + bytes + 255) & ~(size_t)255;
        return p;
    };
    float*    cnt      = (float*)alloc((size_t)nn * 4);
    float*    a1       = (float*)alloc((size_t)nn * 4);
    float*    a2       = (float*)alloc((size_t)nn * 4);
    float*    a3       = (float*)alloc((size_t)nn * 4);
    float*    rA       = (float*)alloc((size_t)nn * 4);
    float*    rB       = (float*)alloc((size_t)nn * 4);
    float*    X        = (float*)alloc((4 * D + 2) * 4);
    size_t    zend     = cur;               // zero range end for fallback
    uint32_t* blkhistS = (uint32_t*)alloc((size_t)PNBLK * nb * 4);
    uint32_t* blkhistD = (uint32_t*)alloc((size_t)PNBLK * nb * 4);
    uint32_t* offsS    = (uint32_t*)alloc((size_t)PNBLK * nb * 4);
    uint32_t* offsD    = (uint32_t*)alloc((size_t)PNBLK * nb * 4);
    uint32_t* bstartS  = (uint32_t*)alloc((size_t)(nb + 1) * 4);
    uint32_t* bstartD  = (uint32_t*)alloc((size_t)(nb + 1) * 4);
    uint32_t* sortedS  = (uint32_t*)alloc((size_t)ne * 4);
    uint32_t* sortedD  = (uint32_t*)alloc((size_t)ne * 4);
    const size_t need = cur;

    const int B = 256;
    if (need <= ws_size && nn <= 131071 && nb <= NBMAX) {
        const int chunk = ((ne + PNBLK - 1) / PNBLK + 3) & ~3;
        hipLaunchKernelGGL(hist_kernel, dim3(PNBLK), dim3(512), 0, stream,
                           srcIdx, dstIdx, blkhistS, blkhistD, ne, nb, chunk);
        hipLaunchKernelGGL(binsum_kernel, dim3(2), dim3(512), 0, stream,
                           blkhistS, blkhistD, bstartS, bstartD, X, nb);
        hipLaunchKernelGGL(offsets_kernel, dim3(2 * nb), dim3(64), 0, stream,
                           blkhistS, blkhistD, bstartS, bstartD, offsS, offsD, nb);
        hipLaunchKernelGGL(place_kernel, dim3(PNBLK), dim3(512), 0, stream,
                           srcIdx, dstIdx, offsS, offsD, sortedS, sortedD, ne, nb, chunk);
        hipLaunchKernelGGL(cntb_kernel, dim3(nb), dim3(B), 0, stream,
                           sortedD, bstartD, cnt, rA, nn, 1.0f / (float)nn);
        hipLaunchKernelGGL(scatb_kernel, dim3(nb), dim3(B), 0, stream,
                           sortedS, bstartS, rA, cnt, a1, rB, nn);
        hipLaunchKernelGGL(scatb_kernel, dim3(nb), dim3(B), 0, stream,
                           sortedS, bstartS, rB, cnt, a2, rA, nn);
        hipLaunchKernelGGL(scatb_kernel, dim3(nb), dim3(B), 0, stream,
                           sortedS, bstartS, rA, cnt, a3, (float*)nullptr, nn);
    } else {
        const int zn = (int)(zend / 4);
        hipLaunchKernelGGL(zero_kernel, dim3((zn + B - 1) / B), dim3(B), 0, stream, (float*)d_ws, zn);
        hipLaunchKernelGGL(cnt_kernel,  dim3((ne + B - 1) / B), dim3(B), 0, stream, dstIdx, cnt, ne);
        hipLaunchKernelGGL(r0_kernel,   dim3((nn + B - 1) / B), dim3(B), 0, stream, cnt, rA, nn);
        hipLaunchKernelGGL(scatter_kernel, dim3((ne + B - 1) / B), dim3(B), 0, stream, srcIdx, dstIdx, rA, a1, ne);
        hipLaunchKernelGGL(rdiv_kernel, dim3((nn + B - 1) / B), dim3(B), 0, stream, a1, cnt, rA, nn);
        hipLaunchKernelGGL(scatter_kernel, dim3((ne + B - 1) / B), dim3(B), 0, stream, srcIdx, dstIdx, rA, a2, ne);
        hipLaunchKernelGGL(rdiv_kernel, dim3((nn + B - 1) / B), dim3(B), 0, stream, a2, cnt, rA, nn);
        hipLaunchKernelGGL(scatter_kernel, dim3((ne + B - 1) / B), dim3(B), 0, stream, srcIdx, dstIdx, rA, a3, ne);
    }

    hipLaunchKernelGGL(xpass_kernel, dim3(1024), dim3(B), 0, stream, x, a1, a2, a3, X, nn);
    hipLaunchKernelGGL(final_kernel, dim3(1), dim3(B), 0, stream, X,
                       Wl1, bl1, Wr1, Wl2, bl2, Wr2, Wl3, bl3, Wr3, Wlin, blin, out, nn);
}